// Round 1
// baseline (1798.965 us; speedup 1.0000x reference)
//
#include <hip/hip_runtime.h>

#define IN_D  128
#define HID_D 128
#define OUT_D 64

static inline size_t align256(size_t x) { return (x + 255) & ~(size_t)255; }

// ---- degree & norm ---------------------------------------------------------
__global__ void deg_kernel(const int* __restrict__ dst, int E, int* __restrict__ deg) {
    int i = blockIdx.x * blockDim.x + threadIdx.x;
    if (i < E) atomicAdd(&deg[dst[i]], 1);
}

__global__ void dinv_kernel(const int* __restrict__ deg, float* __restrict__ dinv, int n) {
    int i = blockIdx.x * blockDim.x + threadIdx.x;
    if (i < n) dinv[i] = rsqrtf((float)(deg[i] + 1));   // +1 = self-loop
}

// ---- GEMM: h[n,128] = x[n,128] @ W[128,128] --------------------------------
__global__ __launch_bounds__(128) void gemm_n128(const float* __restrict__ x,
                                                 const float* __restrict__ W,
                                                 float* __restrict__ h, int n) {
    __shared__ float xs[4][IN_D];
    int row0 = blockIdx.x * 4;
    int tid  = threadIdx.x;
    for (int r = 0; r < 4; ++r) {
        int row = row0 + r;
        xs[r][tid] = (row < n) ? x[(size_t)row * IN_D + tid] : 0.0f;
    }
    __syncthreads();
    float acc[4] = {0.f, 0.f, 0.f, 0.f};
    for (int k = 0; k < IN_D; ++k) {
        float w = W[k * HID_D + tid];
        acc[0] += xs[0][k] * w;
        acc[1] += xs[1][k] * w;
        acc[2] += xs[2][k] * w;
        acc[3] += xs[3][k] * w;
    }
    for (int r = 0; r < 4; ++r) {
        int row = row0 + r;
        if (row < n) h[(size_t)row * HID_D + tid] = acc[r];
    }
}

// ---- GEMM: g[n,64] = h[n,128] @ W[128,64] ----------------------------------
__global__ __launch_bounds__(256) void gemm_n64(const float* __restrict__ x,
                                                const float* __restrict__ W,
                                                float* __restrict__ g, int n) {
    __shared__ float xs[16][HID_D];
    int row0 = blockIdx.x * 16;
    for (int i = threadIdx.x; i < 16 * HID_D; i += 256) {
        int r = i >> 7, c = i & 127;
        int row = row0 + r;
        xs[r][c] = (row < n) ? x[(size_t)row * HID_D + c] : 0.0f;
    }
    __syncthreads();
    int col = threadIdx.x & 63;
    int rg  = threadIdx.x >> 6;            // 0..3, each handles 4 rows
    float acc[4] = {0.f, 0.f, 0.f, 0.f};
    for (int k = 0; k < HID_D; ++k) {
        float w = W[k * OUT_D + col];
        acc[0] += xs[rg * 4 + 0][k] * w;
        acc[1] += xs[rg * 4 + 1][k] * w;
        acc[2] += xs[rg * 4 + 2][k] * w;
        acc[3] += xs[rg * 4 + 3][k] * w;
    }
    for (int j = 0; j < 4; ++j) {
        int row = row0 + rg * 4 + j;
        if (row < n) g[(size_t)row * OUT_D + col] = acc[j];
    }
}

// ---- edge scatter: agg[dst] += norm * h[src], D=128 (32 lanes/edge × f4) ---
__global__ void scatter128(const int* __restrict__ src, const int* __restrict__ dst,
                           const float* __restrict__ dinv, const float* __restrict__ h,
                           float* __restrict__ agg, int E) {
    long long t = (long long)blockIdx.x * blockDim.x + threadIdx.x;
    int e    = (int)(t >> 5);
    int lane = (int)(t & 31);
    if (e >= E) return;
    int s = src[e], d = dst[e];
    float norm = dinv[s] * dinv[d];
    const float4 v = *(const float4*)&h[(size_t)s * 128 + lane * 4];
    float* base = &agg[(size_t)d * 128 + lane * 4];
    atomicAdd(base + 0, v.x * norm);
    atomicAdd(base + 1, v.y * norm);
    atomicAdd(base + 2, v.z * norm);
    atomicAdd(base + 3, v.w * norm);
}

// ---- edge scatter, D=64 (16 lanes/edge × f4) -------------------------------
__global__ void scatter64(const int* __restrict__ src, const int* __restrict__ dst,
                          const float* __restrict__ dinv, const float* __restrict__ h,
                          float* __restrict__ agg, int E) {
    long long t = (long long)blockIdx.x * blockDim.x + threadIdx.x;
    int e    = (int)(t >> 4);
    int lane = (int)(t & 15);
    if (e >= E) return;
    int s = src[e], d = dst[e];
    float norm = dinv[s] * dinv[d];
    const float4 v = *(const float4*)&h[(size_t)s * 64 + lane * 4];
    float* base = &agg[(size_t)d * 64 + lane * 4];
    atomicAdd(base + 0, v.x * norm);
    atomicAdd(base + 1, v.y * norm);
    atomicAdd(base + 2, v.z * norm);
    atomicAdd(base + 3, v.w * norm);
}

// ---- self-loop + bias + relu (layer 1), in place on agg -------------------
__global__ void selfloop_relu128(const float* __restrict__ h, const float* __restrict__ dinv,
                                 const float* __restrict__ b, float* __restrict__ agg, int n) {
    long long t = (long long)blockIdx.x * blockDim.x + threadIdx.x;
    int node = (int)(t >> 5);
    int c4   = (int)(t & 31) * 4;
    if (node >= n) return;
    float di = dinv[node];
    float sl = di * di;
    size_t off = (size_t)node * 128 + c4;
    float4 a  = *(float4*)&agg[off];
    float4 hv = *(const float4*)&h[off];
    a.x = fmaxf(a.x + sl * hv.x + b[c4 + 0], 0.0f);
    a.y = fmaxf(a.y + sl * hv.y + b[c4 + 1], 0.0f);
    a.z = fmaxf(a.z + sl * hv.z + b[c4 + 2], 0.0f);
    a.w = fmaxf(a.w + sl * hv.w + b[c4 + 3], 0.0f);
    *(float4*)&agg[off] = a;
}

// ---- self-loop + bias (layer 2, no relu), in place on out ------------------
__global__ void selfloop_bias64(const float* __restrict__ g, const float* __restrict__ dinv,
                                const float* __restrict__ b, float* __restrict__ out, int n) {
    long long t = (long long)blockIdx.x * blockDim.x + threadIdx.x;
    int node = (int)(t >> 4);
    int c4   = (int)(t & 15) * 4;
    if (node >= n) return;
    float di = dinv[node];
    float sl = di * di;
    size_t off = (size_t)node * 64 + c4;
    float4 o  = *(float4*)&out[off];
    float4 gv = *(const float4*)&g[off];
    o.x += sl * gv.x + b[c4 + 0];
    o.y += sl * gv.y + b[c4 + 1];
    o.z += sl * gv.z + b[c4 + 2];
    o.w += sl * gv.w + b[c4 + 3];
    *(float4*)&out[off] = o;
}

extern "C" void kernel_launch(void* const* d_in, const int* in_sizes, int n_in,
                              void* d_out, int out_size, void* d_ws, size_t ws_size,
                              hipStream_t stream) {
    const float* x  = (const float*)d_in[0];
    const int*   ei = (const int*)d_in[1];
    const float* W1 = (const float*)d_in[2];
    const float* b1 = (const float*)d_in[3];
    const float* W2 = (const float*)d_in[4];
    const float* b2 = (const float*)d_in[5];
    float* out = (float*)d_out;

    const int n = in_sizes[0] / IN_D;   // 100000
    const int E = in_sizes[1] / 2;      // 600000
    const int* src = ei;
    const int* dst = ei + E;

    // workspace layout
    char* ws = (char*)d_ws;
    size_t off = 0;
    int*   deg  = (int*)(ws + off);   off += align256((size_t)n * sizeof(int));
    float* dinv = (float*)(ws + off); off += align256((size_t)n * sizeof(float));
    float* h1   = (float*)(ws + off); off += align256((size_t)n * HID_D * sizeof(float));
    float* agg1 = (float*)(ws + off); off += align256((size_t)n * HID_D * sizeof(float));
    float* g    = h1;  // h1 dead after selfloop_relu128; reuse for layer-2 transform

    // --- norms (shared by both layers) ---
    hipMemsetAsync(deg, 0, (size_t)n * sizeof(int), stream);
    deg_kernel<<<(E + 255) / 256, 256, 0, stream>>>(dst, E, deg);
    dinv_kernel<<<(n + 255) / 256, 256, 0, stream>>>(deg, dinv, n);

    // --- layer 1 ---
    gemm_n128<<<(n + 3) / 4, 128, 0, stream>>>(x, W1, h1, n);
    hipMemsetAsync(agg1, 0, (size_t)n * HID_D * sizeof(float), stream);
    {
        long long threads = (long long)E * 32;
        scatter128<<<(threads + 255) / 256, 256, 0, stream>>>(src, dst, dinv, h1, agg1, E);
    }
    {
        long long threads = (long long)n * 32;
        selfloop_relu128<<<(threads + 255) / 256, 256, 0, stream>>>(h1, dinv, b1, agg1, n);
    }

    // --- layer 2 ---
    gemm_n64<<<(n + 15) / 16, 256, 0, stream>>>(agg1, W2, g, n);
    hipMemsetAsync(out, 0, (size_t)n * OUT_D * sizeof(float), stream);
    {
        long long threads = (long long)E * 16;
        scatter64<<<(threads + 255) / 256, 256, 0, stream>>>(src, dst, dinv, g, out, E);
    }
    {
        long long threads = (long long)n * 16;
        selfloop_bias64<<<(threads + 255) / 256, 256, 0, stream>>>(g, dinv, b2, out, n);
    }
}

// Round 2
// 420.942 us; speedup vs baseline: 4.2737x; 4.2737x over previous
//
#include <hip/hip_runtime.h>

#define IN_D  128
#define HID_D 128
#define OUT_D 64
#define SCAN_B 256

static inline size_t align256(size_t x) { return (x + 255) & ~(size_t)255; }

// ---- degree histogram (int atomics, cheap) ---------------------------------
__global__ void deg_kernel(const int* __restrict__ dst, int E, int* __restrict__ deg) {
    int i = blockIdx.x * blockDim.x + threadIdx.x;
    if (i < E) atomicAdd(&deg[dst[i]], 1);
}

__global__ void dinv_kernel(const int* __restrict__ deg, float* __restrict__ dinv, int n) {
    int i = blockIdx.x * blockDim.x + threadIdx.x;
    if (i < n) dinv[i] = rsqrtf((float)(deg[i] + 1));   // +1 = self-loop
}

// ---- exclusive scan of deg -> offs (3-phase) -------------------------------
__global__ void scan1(const int* __restrict__ deg, int* __restrict__ offs,
                      int* __restrict__ bsums, int n) {
    __shared__ int s[SCAN_B];
    int i = blockIdx.x * SCAN_B + threadIdx.x;
    int v = (i < n) ? deg[i] : 0;
    s[threadIdx.x] = v;
    __syncthreads();
    for (int ofs = 1; ofs < SCAN_B; ofs <<= 1) {
        int t = (threadIdx.x >= ofs) ? s[threadIdx.x - ofs] : 0;
        __syncthreads();
        s[threadIdx.x] += t;
        __syncthreads();
    }
    if (i < n) offs[i] = s[threadIdx.x] - v;            // block-local exclusive
    if (threadIdx.x == SCAN_B - 1) bsums[blockIdx.x] = s[SCAN_B - 1];
}

__global__ void scan2(int* __restrict__ bsums, int nb) {
    __shared__ int s[512];
    int v = (threadIdx.x < nb) ? bsums[threadIdx.x] : 0;
    s[threadIdx.x] = v;
    __syncthreads();
    for (int ofs = 1; ofs < 512; ofs <<= 1) {
        int t = (threadIdx.x >= ofs) ? s[threadIdx.x - ofs] : 0;
        __syncthreads();
        s[threadIdx.x] += t;
        __syncthreads();
    }
    if (threadIdx.x < nb) bsums[threadIdx.x] = s[threadIdx.x] - v;  // exclusive
}

__global__ void scan3(int* __restrict__ offs, const int* __restrict__ bsums,
                      int* __restrict__ cursor, int n) {
    int i = blockIdx.x * SCAN_B + threadIdx.x;
    if (i < n) {
        int o = offs[i] + bsums[blockIdx.x];
        offs[i] = o;
        cursor[i] = o;
    }
}

// ---- counting-sort placement: srcs sorted by dst ---------------------------
__global__ void place_kernel(const int* __restrict__ src, const int* __restrict__ dst,
                             int* __restrict__ cursor, int* __restrict__ srcs, int E) {
    int i = blockIdx.x * blockDim.x + threadIdx.x;
    if (i < E) {
        int d = dst[i];
        int pos = atomicAdd(&cursor[d], 1);
        srcs[pos] = src[i];
    }
}

// ---- GEMM: h'[n,128] = dinv[row] * (x[n,128] @ W[128,128]) -----------------
__global__ __launch_bounds__(128) void gemm_n128(const float* __restrict__ x,
                                                 const float* __restrict__ W,
                                                 const float* __restrict__ dinv,
                                                 float* __restrict__ h, int n) {
    __shared__ float xs[4][IN_D];
    int row0 = blockIdx.x * 4;
    int tid  = threadIdx.x;
    for (int r = 0; r < 4; ++r) {
        int row = row0 + r;
        xs[r][tid] = (row < n) ? x[(size_t)row * IN_D + tid] : 0.0f;
    }
    __syncthreads();
    float acc[4] = {0.f, 0.f, 0.f, 0.f};
    for (int k = 0; k < IN_D; ++k) {
        float w = W[k * HID_D + tid];
        acc[0] += xs[0][k] * w;
        acc[1] += xs[1][k] * w;
        acc[2] += xs[2][k] * w;
        acc[3] += xs[3][k] * w;
    }
    for (int r = 0; r < 4; ++r) {
        int row = row0 + r;
        if (row < n) h[(size_t)row * HID_D + tid] = acc[r] * dinv[row];
    }
}

// ---- GEMM: g'[n,64] = dinv[row] * (h[n,128] @ W[128,64]) -------------------
__global__ __launch_bounds__(256) void gemm_n64(const float* __restrict__ x,
                                                const float* __restrict__ W,
                                                const float* __restrict__ dinv,
                                                float* __restrict__ g, int n) {
    __shared__ float xs[16][HID_D];
    int row0 = blockIdx.x * 16;
    for (int i = threadIdx.x; i < 16 * HID_D; i += 256) {
        int r = i >> 7, c = i & 127;
        int row = row0 + r;
        xs[r][c] = (row < n) ? x[(size_t)row * HID_D + c] : 0.0f;
    }
    __syncthreads();
    int col = threadIdx.x & 63;
    int rg  = threadIdx.x >> 6;            // 0..3, each handles 4 rows
    float acc[4] = {0.f, 0.f, 0.f, 0.f};
    for (int k = 0; k < HID_D; ++k) {
        float w = W[k * OUT_D + col];
        acc[0] += xs[rg * 4 + 0][k] * w;
        acc[1] += xs[rg * 4 + 1][k] * w;
        acc[2] += xs[rg * 4 + 2][k] * w;
        acc[3] += xs[rg * 4 + 3][k] * w;
    }
    for (int j = 0; j < 4; ++j) {
        int row = row0 + rg * 4 + j;
        if (row < n) g[(size_t)row * OUT_D + col] = acc[j] * dinv[row];
    }
}

// ---- gather layer 1: one node per 64-lane wave, float2/lane (D=128) --------
// out[d] = relu(dinv[d] * (sum_{s in N(d)} h'[s] + h'[d]) + b)
__global__ __launch_bounds__(256) void gather128(const float* __restrict__ hp,
                                                 const int* __restrict__ srcs,
                                                 const int* __restrict__ offs,
                                                 const int* __restrict__ deg,
                                                 const float* __restrict__ dinv,
                                                 const float* __restrict__ b,
                                                 float* __restrict__ out, int n) {
    int node = (blockIdx.x * 256 + threadIdx.x) >> 6;
    int lane = threadIdx.x & 63;
    if (node >= n) return;
    int start = offs[node];
    int k     = deg[node];
    size_t c  = (size_t)lane * 2;
    float2 acc = *(const float2*)&hp[(size_t)node * 128 + c];   // self-loop term
    for (int j = 0; j < k; ++j) {
        int s = srcs[start + j];
        float2 v = *(const float2*)&hp[(size_t)s * 128 + c];
        acc.x += v.x;
        acc.y += v.y;
    }
    float di = dinv[node];
    float2 bb = *(const float2*)&b[c];
    float2 o;
    o.x = fmaxf(acc.x * di + bb.x, 0.0f);
    o.y = fmaxf(acc.y * di + bb.y, 0.0f);
    *(float2*)&out[(size_t)node * 128 + c] = o;
}

// ---- gather layer 2: one node per 64-lane wave, 1 float/lane (D=64) --------
__global__ __launch_bounds__(256) void gather64(const float* __restrict__ gp,
                                                const int* __restrict__ srcs,
                                                const int* __restrict__ offs,
                                                const int* __restrict__ deg,
                                                const float* __restrict__ dinv,
                                                const float* __restrict__ b,
                                                float* __restrict__ out, int n) {
    int node = (blockIdx.x * 256 + threadIdx.x) >> 6;
    int lane = threadIdx.x & 63;
    if (node >= n) return;
    int start = offs[node];
    int k     = deg[node];
    float acc = gp[(size_t)node * 64 + lane];                   // self-loop term
    for (int j = 0; j < k; ++j) {
        int s = srcs[start + j];
        acc += gp[(size_t)s * 64 + lane];
    }
    out[(size_t)node * 64 + lane] = acc * dinv[node] + b[lane];
}

extern "C" void kernel_launch(void* const* d_in, const int* in_sizes, int n_in,
                              void* d_out, int out_size, void* d_ws, size_t ws_size,
                              hipStream_t stream) {
    const float* x  = (const float*)d_in[0];
    const int*   ei = (const int*)d_in[1];
    const float* W1 = (const float*)d_in[2];
    const float* b1 = (const float*)d_in[3];
    const float* W2 = (const float*)d_in[4];
    const float* b2 = (const float*)d_in[5];
    float* out = (float*)d_out;

    const int n = in_sizes[0] / IN_D;   // 100000
    const int E = in_sizes[1] / 2;      // 600000
    const int* src = ei;
    const int* dst = ei + E;
    const int nblk = (n + SCAN_B - 1) / SCAN_B;   // 391

    // workspace layout (~106.4 MB)
    char* ws = (char*)d_ws;
    size_t off = 0;
    int*   deg    = (int*)(ws + off);   off += align256((size_t)n * sizeof(int));
    float* dinv   = (float*)(ws + off); off += align256((size_t)n * sizeof(float));
    int*   offs   = (int*)(ws + off);   off += align256((size_t)n * sizeof(int));
    int*   cursor = (int*)(ws + off);   off += align256((size_t)n * sizeof(int));
    int*   bsums  = (int*)(ws + off);   off += align256((size_t)nblk * sizeof(int));
    int*   srcs   = (int*)(ws + off);   off += align256((size_t)E * sizeof(int));
    float* h1     = (float*)(ws + off); off += align256((size_t)n * HID_D * sizeof(float));
    float* agg1   = (float*)(ws + off); off += align256((size_t)n * HID_D * sizeof(float));
    float* g      = h1;  // h1 dead after gather128; reuse for layer-2 transform

    // --- CSR build: deg -> dinv -> exclusive scan -> counting-sort place ---
    hipMemsetAsync(deg, 0, (size_t)n * sizeof(int), stream);
    deg_kernel<<<(E + 255) / 256, 256, 0, stream>>>(dst, E, deg);
    dinv_kernel<<<nblk, SCAN_B, 0, stream>>>(deg, dinv, n);
    scan1<<<nblk, SCAN_B, 0, stream>>>(deg, offs, bsums, n);
    scan2<<<1, 512, 0, stream>>>(bsums, nblk);
    scan3<<<nblk, SCAN_B, 0, stream>>>(offs, bsums, cursor, n);
    place_kernel<<<(E + 255) / 256, 256, 0, stream>>>(src, dst, cursor, srcs, E);

    // --- layer 1: h' = dinv*(x@W1); agg1 = relu(dinv*(gather+self) + b1) ---
    gemm_n128<<<(n + 3) / 4, 128, 0, stream>>>(x, W1, dinv, h1, n);
    gather128<<<(n * 4 + 3) / 4 * 64 / 256 + 1, 256, 0, stream>>>(h1, srcs, offs, deg, dinv, b1, agg1, n);

    // --- layer 2: g' = dinv*(agg1@W2); out = dinv*(gather+self) + b2 ---
    gemm_n64<<<(n + 15) / 16, 256, 0, stream>>>(agg1, W2, dinv, g, n);
    gather64<<<(n * 64 + 255) / 256, 256, 0, stream>>>(g, srcs, offs, deg, dinv, b2, out, n);
}

// Round 3
// 366.574 us; speedup vs baseline: 4.9075x; 1.1483x over previous
//
#include <hip/hip_runtime.h>

#define IN_D  128
#define HID_D 128
#define OUT_D 64
#define SCAN_B 256

static inline size_t align256(size_t x) { return (x + 255) & ~(size_t)255; }

__device__ __forceinline__ void fma4(float4& a, float s, const float4& w) {
    a.x = fmaf(s, w.x, a.x);
    a.y = fmaf(s, w.y, a.y);
    a.z = fmaf(s, w.z, a.z);
    a.w = fmaf(s, w.w, a.w);
}

// ---- degree histogram (int atomics, cheap) ---------------------------------
__global__ void deg_kernel(const int* __restrict__ dst, int E, int* __restrict__ deg) {
    int i = blockIdx.x * blockDim.x + threadIdx.x;
    if (i < E) atomicAdd(&deg[dst[i]], 1);
}

__global__ void dinv_kernel(const int* __restrict__ deg, float* __restrict__ dinv, int n) {
    int i = blockIdx.x * blockDim.x + threadIdx.x;
    if (i < n) dinv[i] = rsqrtf((float)(deg[i] + 1));   // +1 = self-loop
}

// ---- exclusive scan of deg -> offs (3-phase) -------------------------------
__global__ void scan1(const int* __restrict__ deg, int* __restrict__ offs,
                      int* __restrict__ bsums, int n) {
    __shared__ int s[SCAN_B];
    int i = blockIdx.x * SCAN_B + threadIdx.x;
    int v = (i < n) ? deg[i] : 0;
    s[threadIdx.x] = v;
    __syncthreads();
    for (int ofs = 1; ofs < SCAN_B; ofs <<= 1) {
        int t = (threadIdx.x >= ofs) ? s[threadIdx.x - ofs] : 0;
        __syncthreads();
        s[threadIdx.x] += t;
        __syncthreads();
    }
    if (i < n) offs[i] = s[threadIdx.x] - v;            // block-local exclusive
    if (threadIdx.x == SCAN_B - 1) bsums[blockIdx.x] = s[SCAN_B - 1];
}

__global__ void scan2(int* __restrict__ bsums, int nb) {
    __shared__ int s[512];
    int v = (threadIdx.x < nb) ? bsums[threadIdx.x] : 0;
    s[threadIdx.x] = v;
    __syncthreads();
    for (int ofs = 1; ofs < 512; ofs <<= 1) {
        int t = (threadIdx.x >= ofs) ? s[threadIdx.x - ofs] : 0;
        __syncthreads();
        s[threadIdx.x] += t;
        __syncthreads();
    }
    if (threadIdx.x < nb) bsums[threadIdx.x] = s[threadIdx.x] - v;  // exclusive
}

__global__ void scan3(int* __restrict__ offs, const int* __restrict__ bsums,
                      int* __restrict__ cursor, int n) {
    int i = blockIdx.x * SCAN_B + threadIdx.x;
    if (i < n) {
        int o = offs[i] + bsums[blockIdx.x];
        offs[i] = o;
        cursor[i] = o;
    }
}

// ---- counting-sort placement: srcs sorted by dst ---------------------------
__global__ void place_kernel(const int* __restrict__ src, const int* __restrict__ dst,
                             int* __restrict__ cursor, int* __restrict__ srcs, int E) {
    int i = blockIdx.x * blockDim.x + threadIdx.x;
    if (i < E) {
        int d = dst[i];
        int pos = atomicAdd(&cursor[d], 1);
        srcs[pos] = src[i];
    }
}

// ---- GEMM1: h'[n,128] = dinv[row] * (x[n,128] @ W[128,128]) ----------------
// 256 thr: 32 rows x 128 cols / block; 4x4 micro-tile; W staged in 2 K-halves.
__global__ __launch_bounds__(256, 4) void gemm1(const float* __restrict__ x,
                                                const float* __restrict__ W,
                                                const float* __restrict__ dinv,
                                                float* __restrict__ h, int n) {
    __shared__ float Ws[64 * 128];               // 32 KB
    const int c0 = (threadIdx.x & 31) * 4;       // col group
    const int rg = threadIdx.x >> 5;             // 0..7 row group
    const int row0 = blockIdx.x * 32 + rg * 4;
    int r[4];
#pragma unroll
    for (int i = 0; i < 4; ++i) r[i] = min(row0 + i, n - 1);
    float4 acc[4] = {make_float4(0, 0, 0, 0), make_float4(0, 0, 0, 0),
                     make_float4(0, 0, 0, 0), make_float4(0, 0, 0, 0)};

    for (int half = 0; half < 2; ++half) {
        {   // stage W rows [half*64, half*64+64) into LDS
            const float4* Wg = (const float4*)(W + half * 64 * 128);
            float4* Wl = (float4*)Ws;
            for (int i = threadIdx.x; i < 64 * 128 / 4; i += 256) Wl[i] = Wg[i];
        }
        __syncthreads();
        const float* xb = x + half * 64;
#pragma unroll 4
        for (int k0 = 0; k0 < 64; k0 += 4) {
            float4 xv[4];
#pragma unroll
            for (int i = 0; i < 4; ++i)
                xv[i] = *(const float4*)&xb[(size_t)r[i] * IN_D + k0];
            float4 w0 = *(const float4*)&Ws[(k0 + 0) * 128 + c0];
            float4 w1 = *(const float4*)&Ws[(k0 + 1) * 128 + c0];
            float4 w2 = *(const float4*)&Ws[(k0 + 2) * 128 + c0];
            float4 w3 = *(const float4*)&Ws[(k0 + 3) * 128 + c0];
#pragma unroll
            for (int i = 0; i < 4; ++i) {
                fma4(acc[i], xv[i].x, w0);
                fma4(acc[i], xv[i].y, w1);
                fma4(acc[i], xv[i].z, w2);
                fma4(acc[i], xv[i].w, w3);
            }
        }
        __syncthreads();
    }
#pragma unroll
    for (int i = 0; i < 4; ++i) {
        int row = row0 + i;
        if (row < n) {
            float di = dinv[row];
            float4 o = acc[i];
            o.x *= di; o.y *= di; o.z *= di; o.w *= di;
            *(float4*)&h[(size_t)row * HID_D + c0] = o;
        }
    }
}

// ---- GEMM2: g'[n,64] = dinv[row] * (h[n,128] @ W[128,64]) ------------------
// 256 thr: 64 rows x 64 cols / block; 4x4 micro-tile; W2 (32 KB) staged once.
__global__ __launch_bounds__(256, 4) void gemm2(const float* __restrict__ x,
                                                const float* __restrict__ W,
                                                const float* __restrict__ dinv,
                                                float* __restrict__ g, int n) {
    __shared__ float Ws[128 * 64];               // 32 KB
    const int c0 = (threadIdx.x & 15) * 4;       // col group (64 cols)
    const int rg = threadIdx.x >> 4;             // 0..15 row group
    const int row0 = blockIdx.x * 64 + rg * 4;
    int r[4];
#pragma unroll
    for (int i = 0; i < 4; ++i) r[i] = min(row0 + i, n - 1);
    float4 acc[4] = {make_float4(0, 0, 0, 0), make_float4(0, 0, 0, 0),
                     make_float4(0, 0, 0, 0), make_float4(0, 0, 0, 0)};

    {   // stage W2
        const float4* Wg = (const float4*)W;
        float4* Wl = (float4*)Ws;
        for (int i = threadIdx.x; i < 128 * 64 / 4; i += 256) Wl[i] = Wg[i];
    }
    __syncthreads();
#pragma unroll 4
    for (int k0 = 0; k0 < 128; k0 += 4) {
        float4 xv[4];
#pragma unroll
        for (int i = 0; i < 4; ++i)
            xv[i] = *(const float4*)&x[(size_t)r[i] * HID_D + k0];
        float4 w0 = *(const float4*)&Ws[(k0 + 0) * 64 + c0];
        float4 w1 = *(const float4*)&Ws[(k0 + 1) * 64 + c0];
        float4 w2 = *(const float4*)&Ws[(k0 + 2) * 64 + c0];
        float4 w3 = *(const float4*)&Ws[(k0 + 3) * 64 + c0];
#pragma unroll
        for (int i = 0; i < 4; ++i) {
            fma4(acc[i], xv[i].x, w0);
            fma4(acc[i], xv[i].y, w1);
            fma4(acc[i], xv[i].z, w2);
            fma4(acc[i], xv[i].w, w3);
        }
    }
#pragma unroll
    for (int i = 0; i < 4; ++i) {
        int row = row0 + i;
        if (row < n) {
            float di = dinv[row];
            float4 o = acc[i];
            o.x *= di; o.y *= di; o.z *= di; o.w *= di;
            *(float4*)&g[(size_t)row * OUT_D + c0] = o;
        }
    }
}

// ---- gather layer 1: one node per 64-lane wave, float2/lane (D=128) --------
// out[d] = relu(dinv[d] * (sum_{s in N(d)} h'[s] + h'[d]) + b)
__global__ __launch_bounds__(256) void gather128(const float* __restrict__ hp,
                                                 const int* __restrict__ srcs,
                                                 const int* __restrict__ offs,
                                                 const int* __restrict__ deg,
                                                 const float* __restrict__ dinv,
                                                 const float* __restrict__ b,
                                                 float* __restrict__ out, int n) {
    int node = (blockIdx.x * 256 + threadIdx.x) >> 6;
    int lane = threadIdx.x & 63;
    if (node >= n) return;
    int start = offs[node];
    int k     = deg[node];
    const float* hpc = hp + (size_t)lane * 2;
    float2 acc  = *(const float2*)&hpc[(size_t)node * 128];   // self-loop term
    float2 acc1 = make_float2(0.0f, 0.0f);
    int j = 0;
    for (; j + 4 <= k; j += 4) {
        int s0 = srcs[start + j + 0];
        int s1 = srcs[start + j + 1];
        int s2 = srcs[start + j + 2];
        int s3 = srcs[start + j + 3];
        float2 v0 = *(const float2*)&hpc[(size_t)s0 * 128];
        float2 v1 = *(const float2*)&hpc[(size_t)s1 * 128];
        float2 v2 = *(const float2*)&hpc[(size_t)s2 * 128];
        float2 v3 = *(const float2*)&hpc[(size_t)s3 * 128];
        acc.x  += v0.x + v2.x;  acc.y  += v0.y + v2.y;
        acc1.x += v1.x + v3.x;  acc1.y += v1.y + v3.y;
    }
    for (; j < k; ++j) {
        int s = srcs[start + j];
        float2 v = *(const float2*)&hpc[(size_t)s * 128];
        acc.x += v.x; acc.y += v.y;
    }
    acc.x += acc1.x; acc.y += acc1.y;
    float di = dinv[node];
    float2 bb = *(const float2*)&b[(size_t)lane * 2];
    float2 o;
    o.x = fmaxf(acc.x * di + bb.x, 0.0f);
    o.y = fmaxf(acc.y * di + bb.y, 0.0f);
    *(float2*)&out[(size_t)node * 128 + (size_t)lane * 2] = o;
}

// ---- gather layer 2: one node per 64-lane wave, 1 float/lane (D=64) --------
__global__ __launch_bounds__(256) void gather64(const float* __restrict__ gp,
                                                const int* __restrict__ srcs,
                                                const int* __restrict__ offs,
                                                const int* __restrict__ deg,
                                                const float* __restrict__ dinv,
                                                const float* __restrict__ b,
                                                float* __restrict__ out, int n) {
    int node = (blockIdx.x * 256 + threadIdx.x) >> 6;
    int lane = threadIdx.x & 63;
    if (node >= n) return;
    int start = offs[node];
    int k     = deg[node];
    const float* gpc = gp + lane;
    float acc  = gpc[(size_t)node * 64];                     // self-loop term
    float acc1 = 0.0f;
    int j = 0;
    for (; j + 4 <= k; j += 4) {
        int s0 = srcs[start + j + 0];
        int s1 = srcs[start + j + 1];
        int s2 = srcs[start + j + 2];
        int s3 = srcs[start + j + 3];
        float v0 = gpc[(size_t)s0 * 64];
        float v1 = gpc[(size_t)s1 * 64];
        float v2 = gpc[(size_t)s2 * 64];
        float v3 = gpc[(size_t)s3 * 64];
        acc  += v0 + v2;
        acc1 += v1 + v3;
    }
    for (; j < k; ++j) {
        int s = srcs[start + j];
        acc += gpc[(size_t)s * 64];
    }
    acc += acc1;
    out[(size_t)node * 64 + lane] = acc * dinv[node] + b[lane];
}

extern "C" void kernel_launch(void* const* d_in, const int* in_sizes, int n_in,
                              void* d_out, int out_size, void* d_ws, size_t ws_size,
                              hipStream_t stream) {
    const float* x  = (const float*)d_in[0];
    const int*   ei = (const int*)d_in[1];
    const float* W1 = (const float*)d_in[2];
    const float* b1 = (const float*)d_in[3];
    const float* W2 = (const float*)d_in[4];
    const float* b2 = (const float*)d_in[5];
    float* out = (float*)d_out;

    const int n = in_sizes[0] / IN_D;   // 100000
    const int E = in_sizes[1] / 2;      // 600000
    const int* src = ei;
    const int* dst = ei + E;
    const int nblk = (n + SCAN_B - 1) / SCAN_B;   // 391

    // workspace layout (~106.4 MB)
    char* ws = (char*)d_ws;
    size_t off = 0;
    int*   deg    = (int*)(ws + off);   off += align256((size_t)n * sizeof(int));
    float* dinv   = (float*)(ws + off); off += align256((size_t)n * sizeof(float));
    int*   offs   = (int*)(ws + off);   off += align256((size_t)n * sizeof(int));
    int*   cursor = (int*)(ws + off);   off += align256((size_t)n * sizeof(int));
    int*   bsums  = (int*)(ws + off);   off += align256((size_t)nblk * sizeof(int));
    int*   srcs   = (int*)(ws + off);   off += align256((size_t)E * sizeof(int));
    float* h1     = (float*)(ws + off); off += align256((size_t)n * HID_D * sizeof(float));
    float* agg1   = (float*)(ws + off); off += align256((size_t)n * HID_D * sizeof(float));
    float* g      = h1;  // h1 dead after gather128; reuse for layer-2 transform

    // --- CSR build: deg -> dinv -> exclusive scan -> counting-sort place ---
    hipMemsetAsync(deg, 0, (size_t)n * sizeof(int), stream);
    deg_kernel<<<(E + 255) / 256, 256, 0, stream>>>(dst, E, deg);
    dinv_kernel<<<nblk, SCAN_B, 0, stream>>>(deg, dinv, n);
    scan1<<<nblk, SCAN_B, 0, stream>>>(deg, offs, bsums, n);
    scan2<<<1, 512, 0, stream>>>(bsums, nblk);
    scan3<<<nblk, SCAN_B, 0, stream>>>(offs, bsums, cursor, n);
    place_kernel<<<(E + 255) / 256, 256, 0, stream>>>(src, dst, cursor, srcs, E);

    // --- layer 1: h' = dinv*(x@W1); agg1 = relu(dinv*(gather+self) + b1) ---
    gemm1<<<(n + 31) / 32, 256, 0, stream>>>(x, W1, dinv, h1, n);
    gather128<<<(n + 3) / 4, 256, 0, stream>>>(h1, srcs, offs, deg, dinv, b1, agg1, n);

    // --- layer 2: g' = dinv*(agg1@W2); out = dinv*(gather+self) + b2 ---
    gemm2<<<(n + 63) / 64, 256, 0, stream>>>(agg1, W2, dinv, g, n);
    gather64<<<(n + 3) / 4, 256, 0, stream>>>(g, srcs, offs, deg, dinv, b2, out, n);
}

// Round 4
// 270.357 us; speedup vs baseline: 6.6540x; 1.3559x over previous
//
#include <hip/hip_runtime.h>

#define IN_D  128
#define HID_D 128
#define OUT_D 64
#define SCAN_B 256

static inline size_t align256(size_t x) { return (x + 255) & ~(size_t)255; }

typedef short bf8_t  __attribute__((ext_vector_type(8)));   // 8 bf16 (4 VGPRs)
typedef float f32x4  __attribute__((ext_vector_type(4)));   // 4 fp32 acc

union BF8 { bf8_t v; unsigned short u[8]; uint4 q; };

__device__ __forceinline__ unsigned short f2bf(float f) {   // RNE fp32->bf16
    unsigned int u = __float_as_uint(f);
    u += 0x7FFF + ((u >> 16) & 1);
    return (unsigned short)(u >> 16);
}
__device__ __forceinline__ float bflo(unsigned int u) { return __uint_as_float(u << 16); }
__device__ __forceinline__ float bfhi(unsigned int u) { return __uint_as_float(u & 0xFFFF0000u); }
__device__ __forceinline__ float bf2f(unsigned short h) { return __uint_as_float((unsigned int)h << 16); }

// ---- degree histogram ------------------------------------------------------
__global__ void deg_kernel(const int* __restrict__ dst, int E, int* __restrict__ deg) {
    int i = blockIdx.x * blockDim.x + threadIdx.x;
    if (i < E) atomicAdd(&deg[dst[i]], 1);
}

__global__ void dinv_kernel(const int* __restrict__ deg, float* __restrict__ dinv, int n) {
    int i = blockIdx.x * blockDim.x + threadIdx.x;
    if (i < n) dinv[i] = rsqrtf((float)(deg[i] + 1));   // +1 = self-loop
}

// ---- exclusive scan of deg -> offs (3-phase) -------------------------------
__global__ void scan1(const int* __restrict__ deg, int* __restrict__ offs,
                      int* __restrict__ bsums, int n) {
    __shared__ int s[SCAN_B];
    int i = blockIdx.x * SCAN_B + threadIdx.x;
    int v = (i < n) ? deg[i] : 0;
    s[threadIdx.x] = v;
    __syncthreads();
    for (int ofs = 1; ofs < SCAN_B; ofs <<= 1) {
        int t = (threadIdx.x >= ofs) ? s[threadIdx.x - ofs] : 0;
        __syncthreads();
        s[threadIdx.x] += t;
        __syncthreads();
    }
    if (i < n) offs[i] = s[threadIdx.x] - v;
    if (threadIdx.x == SCAN_B - 1) bsums[blockIdx.x] = s[SCAN_B - 1];
}

__global__ void scan2(int* __restrict__ bsums, int nb) {
    __shared__ int s[512];
    int v = (threadIdx.x < nb) ? bsums[threadIdx.x] : 0;
    s[threadIdx.x] = v;
    __syncthreads();
    for (int ofs = 1; ofs < 512; ofs <<= 1) {
        int t = (threadIdx.x >= ofs) ? s[threadIdx.x - ofs] : 0;
        __syncthreads();
        s[threadIdx.x] += t;
        __syncthreads();
    }
    if (threadIdx.x < nb) bsums[threadIdx.x] = s[threadIdx.x] - v;
}

__global__ void scan3(int* __restrict__ offs, const int* __restrict__ bsums,
                      int* __restrict__ cursor, int n) {
    int i = blockIdx.x * SCAN_B + threadIdx.x;
    if (i < n) {
        int o = offs[i] + bsums[blockIdx.x];
        offs[i] = o;
        cursor[i] = o;
    }
}

// ---- counting-sort placement: srcs sorted by dst ---------------------------
__global__ void place_kernel(const int* __restrict__ src, const int* __restrict__ dst,
                             int* __restrict__ cursor, int* __restrict__ srcs, int E) {
    int i = blockIdx.x * blockDim.x + threadIdx.x;
    if (i < E) {
        int d = dst[i];
        int pos = atomicAdd(&cursor[d], 1);
        srcs[pos] = src[i];
    }
}

// ---- W pre-swizzle into MFMA B-fragment order, fp32 -> bf16 ----------------
// frag layout: B[k = kk*32 + (lane>>4)*8 + j][col = t*16 + (lane&15)], j=0..7 contig
__global__ void prep_W(const float* __restrict__ W1, const float* __restrict__ W2,
                       unsigned short* __restrict__ Wb1, unsigned short* __restrict__ Wb2) {
    int i = blockIdx.x * 256 + threadIdx.x;
    if (i < 4096) {                       // W1: kk(4) x t(8) x lane(64)
        int L = i & 63, t = (i >> 6) & 7, kk = i >> 9;
        int kbase = kk * 32 + (L >> 4) * 8;
        int col = t * 16 + (L & 15);
        unsigned short* o = Wb1 + (size_t)i * 8;
#pragma unroll
        for (int j = 0; j < 8; ++j) o[j] = f2bf(W1[(size_t)(kbase + j) * HID_D + col]);
    } else if (i < 6144) {                // W2: kk(4) x t(4) x lane(64)
        int r = i - 4096;
        int L = r & 63, t = (r >> 6) & 3, kk = r >> 8;
        int kbase = kk * 32 + (L >> 4) * 8;
        int col = t * 16 + (L & 15);
        unsigned short* o = Wb2 + (size_t)r * 8;
#pragma unroll
        for (int j = 0; j < 8; ++j) o[j] = f2bf(W2[(size_t)(kbase + j) * OUT_D + col]);
    }
}

// ---- GEMM1 (MFMA): h[n,128]bf16 = dinv[row] * (x[n,128]f32 @ W1) -----------
// block 256 = 4 waves; 64 rows x 128 cols; wave: 16 rows, 8 N-tiles, 4 K-steps
__global__ __launch_bounds__(256) void gemm1(const float* __restrict__ x,
                                             const unsigned short* __restrict__ Wb,
                                             const float* __restrict__ dinv,
                                             unsigned short* __restrict__ h, int n) {
    __shared__ __align__(16) unsigned short Ws[4 * 8 * 64 * 8];   // 32 KB
    {   // stage swizzled W (already frag-ordered)
        const uint4* g = (const uint4*)Wb;
        uint4* l = (uint4*)Ws;
        for (int i = threadIdx.x; i < 2048; i += 256) l[i] = g[i];
    }
    const int wave = threadIdx.x >> 6, lane = threadIdx.x & 63;
    const int wrow0 = blockIdx.x * 64 + wave * 16;
    const int mrow = min(wrow0 + (lane & 15), n - 1);
    const float* xr = x + (size_t)mrow * IN_D + ((lane >> 4) * 8);

    float4 a0[4], a1[4];
#pragma unroll
    for (int kk = 0; kk < 4; ++kk) {
        a0[kk] = *(const float4*)(xr + kk * 32);
        a1[kk] = *(const float4*)(xr + kk * 32 + 4);
    }
    BF8 af[4];
#pragma unroll
    for (int kk = 0; kk < 4; ++kk) {
        af[kk].u[0] = f2bf(a0[kk].x); af[kk].u[1] = f2bf(a0[kk].y);
        af[kk].u[2] = f2bf(a0[kk].z); af[kk].u[3] = f2bf(a0[kk].w);
        af[kk].u[4] = f2bf(a1[kk].x); af[kk].u[5] = f2bf(a1[kk].y);
        af[kk].u[6] = f2bf(a1[kk].z); af[kk].u[7] = f2bf(a1[kk].w);
    }
    __syncthreads();

    f32x4 acc[8];
#pragma unroll
    for (int t = 0; t < 8; ++t) acc[t] = (f32x4){0.f, 0.f, 0.f, 0.f};
    const bf8_t* B = (const bf8_t*)Ws;
#pragma unroll
    for (int kk = 0; kk < 4; ++kk) {
#pragma unroll
        for (int t = 0; t < 8; ++t) {
            bf8_t b = B[(kk * 8 + t) * 64 + lane];
            acc[t] = __builtin_amdgcn_mfma_f32_16x16x32_bf16(af[kk].v, b, acc[t], 0, 0, 0);
        }
    }
    // epilogue: D[row = quad*4+r][col = t*16 + (lane&15)]
    const int q = lane >> 4, cbase = lane & 15;
    int rr[4]; float di[4];
#pragma unroll
    for (int r = 0; r < 4; ++r) {
        rr[r] = wrow0 + q * 4 + r;
        di[r] = dinv[min(rr[r], n - 1)];
    }
#pragma unroll
    for (int t = 0; t < 8; ++t) {
        int col = t * 16 + cbase;
#pragma unroll
        for (int r = 0; r < 4; ++r)
            if (rr[r] < n) h[(size_t)rr[r] * HID_D + col] = f2bf(acc[t][r] * di[r]);
    }
}

// ---- GEMM2 (MFMA): g[n,64]bf16 = dinv[row] * (agg[n,128]bf16 @ W2) ---------
__global__ __launch_bounds__(256) void gemm2(const unsigned short* __restrict__ a,
                                             const unsigned short* __restrict__ Wb,
                                             const float* __restrict__ dinv,
                                             unsigned short* __restrict__ g2, int n) {
    __shared__ __align__(16) unsigned short Ws[4 * 4 * 64 * 8];   // 16 KB
    {
        const uint4* g = (const uint4*)Wb;
        uint4* l = (uint4*)Ws;
        for (int i = threadIdx.x; i < 1024; i += 256) l[i] = g[i];
    }
    const int wave = threadIdx.x >> 6, lane = threadIdx.x & 63;
    const int wrow0 = blockIdx.x * 64 + wave * 16;
    const int mrow = min(wrow0 + (lane & 15), n - 1);
    const uint4* ar = (const uint4*)(a + (size_t)mrow * HID_D + ((lane >> 4) * 8));

    BF8 af[4];
#pragma unroll
    for (int kk = 0; kk < 4; ++kk) af[kk].q = ar[kk * 4];   // +32 bf16 per K-step
    __syncthreads();

    f32x4 acc[4];
#pragma unroll
    for (int t = 0; t < 4; ++t) acc[t] = (f32x4){0.f, 0.f, 0.f, 0.f};
    const bf8_t* B = (const bf8_t*)Ws;
#pragma unroll
    for (int kk = 0; kk < 4; ++kk) {
#pragma unroll
        for (int t = 0; t < 4; ++t) {
            bf8_t b = B[(kk * 4 + t) * 64 + lane];
            acc[t] = __builtin_amdgcn_mfma_f32_16x16x32_bf16(af[kk].v, b, acc[t], 0, 0, 0);
        }
    }
    const int q = lane >> 4, cbase = lane & 15;
    int rr[4]; float di[4];
#pragma unroll
    for (int r = 0; r < 4; ++r) {
        rr[r] = wrow0 + q * 4 + r;
        di[r] = dinv[min(rr[r], n - 1)];
    }
#pragma unroll
    for (int t = 0; t < 4; ++t) {
        int col = t * 16 + cbase;
#pragma unroll
        for (int r = 0; r < 4; ++r)
            if (rr[r] < n) g2[(size_t)rr[r] * OUT_D + col] = f2bf(acc[t][r] * di[r]);
    }
}

// ---- gather layer 1: one node/wave; hp bf16 (256 B/row); out agg bf16 ------
__global__ __launch_bounds__(256) void gather128(const unsigned short* __restrict__ hp,
                                                 const int* __restrict__ srcs,
                                                 const int* __restrict__ offs,
                                                 const int* __restrict__ deg,
                                                 const float* __restrict__ dinv,
                                                 const float* __restrict__ b,
                                                 unsigned int* __restrict__ out, int n) {
    int node = (blockIdx.x * 256 + threadIdx.x) >> 6;
    int lane = threadIdx.x & 63;
    if (node >= n) return;
    int start = offs[node];
    int k     = deg[node];
    const unsigned int* hp32 = (const unsigned int*)hp + lane;  // 2 bf16 / lane
    unsigned int u = hp32[(size_t)node * 64];                   // self-loop term
    float ax = bflo(u), ay = bfhi(u);
    float bx = 0.f, by = 0.f;
    int j = 0;
    for (; j + 4 <= k; j += 4) {
        int s0 = srcs[start + j + 0];
        int s1 = srcs[start + j + 1];
        int s2 = srcs[start + j + 2];
        int s3 = srcs[start + j + 3];
        unsigned int u0 = hp32[(size_t)s0 * 64];
        unsigned int u1 = hp32[(size_t)s1 * 64];
        unsigned int u2 = hp32[(size_t)s2 * 64];
        unsigned int u3 = hp32[(size_t)s3 * 64];
        ax += bflo(u0) + bflo(u2); ay += bfhi(u0) + bfhi(u2);
        bx += bflo(u1) + bflo(u3); by += bfhi(u1) + bfhi(u3);
    }
    for (; j < k; ++j) {
        unsigned int uj = hp32[(size_t)srcs[start + j] * 64];
        ax += bflo(uj); ay += bfhi(uj);
    }
    ax += bx; ay += by;
    float di = dinv[node];
    float2 bb = *(const float2*)&b[(size_t)lane * 2];
    float ox = fmaxf(ax * di + bb.x, 0.0f);
    float oy = fmaxf(ay * di + bb.y, 0.0f);
    out[(size_t)node * 64 + lane] = (unsigned int)f2bf(ox) | ((unsigned int)f2bf(oy) << 16);
}

// ---- gather layer 2: one node/wave; gp bf16 (128 B/row); out fp32 ----------
__global__ __launch_bounds__(256) void gather64(const unsigned short* __restrict__ gp,
                                                const int* __restrict__ srcs,
                                                const int* __restrict__ offs,
                                                const int* __restrict__ deg,
                                                const float* __restrict__ dinv,
                                                const float* __restrict__ b,
                                                float* __restrict__ out, int n) {
    int node = (blockIdx.x * 256 + threadIdx.x) >> 6;
    int lane = threadIdx.x & 63;
    if (node >= n) return;
    int start = offs[node];
    int k     = deg[node];
    const unsigned short* gpc = gp + lane;
    float acc  = bf2f(gpc[(size_t)node * 64]);      // self-loop term
    float acc1 = 0.0f;
    int j = 0;
    for (; j + 4 <= k; j += 4) {
        int s0 = srcs[start + j + 0];
        int s1 = srcs[start + j + 1];
        int s2 = srcs[start + j + 2];
        int s3 = srcs[start + j + 3];
        float v0 = bf2f(gpc[(size_t)s0 * 64]);
        float v1 = bf2f(gpc[(size_t)s1 * 64]);
        float v2 = bf2f(gpc[(size_t)s2 * 64]);
        float v3 = bf2f(gpc[(size_t)s3 * 64]);
        acc  += v0 + v2;
        acc1 += v1 + v3;
    }
    for (; j < k; ++j) acc += bf2f(gpc[(size_t)srcs[start + j] * 64]);
    acc += acc1;
    out[(size_t)node * 64 + lane] = acc * dinv[node] + b[lane];
}

extern "C" void kernel_launch(void* const* d_in, const int* in_sizes, int n_in,
                              void* d_out, int out_size, void* d_ws, size_t ws_size,
                              hipStream_t stream) {
    const float* x  = (const float*)d_in[0];
    const int*   ei = (const int*)d_in[1];
    const float* W1 = (const float*)d_in[2];
    const float* b1 = (const float*)d_in[3];
    const float* W2 = (const float*)d_in[4];
    const float* b2 = (const float*)d_in[5];
    float* out = (float*)d_out;

    const int n = in_sizes[0] / IN_D;   // 100000
    const int E = in_sizes[1] / 2;      // 600000
    const int* src = ei;
    const int* dst = ei + E;
    const int nblk = (n + SCAN_B - 1) / SCAN_B;

    // workspace layout (~60 MB)
    char* ws = (char*)d_ws;
    size_t off = 0;
    int*   deg    = (int*)(ws + off);   off += align256((size_t)n * sizeof(int));
    float* dinv   = (float*)(ws + off); off += align256((size_t)n * sizeof(float));
    int*   offs   = (int*)(ws + off);   off += align256((size_t)n * sizeof(int));
    int*   cursor = (int*)(ws + off);   off += align256((size_t)n * sizeof(int));
    int*   bsums  = (int*)(ws + off);   off += align256((size_t)nblk * sizeof(int));
    int*   srcs   = (int*)(ws + off);   off += align256((size_t)E * sizeof(int));
    unsigned short* Wb1 = (unsigned short*)(ws + off); off += align256(4096 * 8 * sizeof(unsigned short));
    unsigned short* Wb2 = (unsigned short*)(ws + off); off += align256(2048 * 8 * sizeof(unsigned short));
    unsigned short* h1  = (unsigned short*)(ws + off); off += align256((size_t)n * HID_D * sizeof(unsigned short));
    unsigned short* agg1= (unsigned short*)(ws + off); off += align256((size_t)n * HID_D * sizeof(unsigned short));
    unsigned short* g2  = h1;   // h1 dead after gather128; reuse (needs n*64 <= n*128) ✓

    // --- CSR build + weight prep ---
    hipMemsetAsync(deg, 0, (size_t)n * sizeof(int), stream);
    deg_kernel<<<(E + 255) / 256, 256, 0, stream>>>(dst, E, deg);
    dinv_kernel<<<nblk, SCAN_B, 0, stream>>>(deg, dinv, n);
    scan1<<<nblk, SCAN_B, 0, stream>>>(deg, offs, bsums, n);
    scan2<<<1, 512, 0, stream>>>(bsums, nblk);
    scan3<<<nblk, SCAN_B, 0, stream>>>(offs, bsums, cursor, n);
    place_kernel<<<(E + 255) / 256, 256, 0, stream>>>(src, dst, cursor, srcs, E);
    prep_W<<<24, 256, 0, stream>>>(W1, W2, Wb1, Wb2);

    // --- layer 1 ---
    gemm1<<<(n + 63) / 64, 256, 0, stream>>>(x, Wb1, dinv, h1, n);
    gather128<<<(n + 3) / 4, 256, 0, stream>>>(h1, srcs, offs, deg, dinv, b1,
                                               (unsigned int*)agg1, n);

    // --- layer 2 ---
    gemm2<<<(n + 63) / 64, 256, 0, stream>>>(agg1, Wb2, dinv, g2, n);
    gather64<<<(n + 3) / 4, 256, 0, stream>>>(g2, srcs, offs, deg, dinv, b2, out, n);
}

// Round 5
// 240.942 us; speedup vs baseline: 7.4664x; 1.1221x over previous
//
#include <hip/hip_runtime.h>

#define IN_D  128
#define HID_D 128
#define OUT_D 64
#define SCAN_B 256

static inline size_t align256(size_t x) { return (x + 255) & ~(size_t)255; }

typedef short bf8_t  __attribute__((ext_vector_type(8)));   // 8 bf16 (4 VGPRs)
typedef float f32x4  __attribute__((ext_vector_type(4)));   // 4 fp32 acc

union BF8 { bf8_t v; unsigned short u[8]; uint4 q; };

__device__ __forceinline__ unsigned short f2bf(float f) {   // RNE fp32->bf16
    unsigned int u = __float_as_uint(f);
    u += 0x7FFF + ((u >> 16) & 1);
    return (unsigned short)(u >> 16);
}
__device__ __forceinline__ float bflo(unsigned int u) { return __uint_as_float(u << 16); }
__device__ __forceinline__ float bfhi(unsigned int u) { return __uint_as_float(u & 0xFFFF0000u); }

__device__ __forceinline__ void acc8(float* a, uint4 v) {
    a[0] += bflo(v.x); a[1] += bfhi(v.x);
    a[2] += bflo(v.y); a[3] += bfhi(v.y);
    a[4] += bflo(v.z); a[5] += bfhi(v.z);
    a[6] += bflo(v.w); a[7] += bfhi(v.w);
}

// ---- degree histogram ------------------------------------------------------
__global__ void deg_kernel(const int* __restrict__ dst, int E, int* __restrict__ deg) {
    int i = blockIdx.x * blockDim.x + threadIdx.x;
    if (i < E) atomicAdd(&deg[dst[i]], 1);
}

__global__ void dinv_kernel(const int* __restrict__ deg, float* __restrict__ dinv, int n) {
    int i = blockIdx.x * blockDim.x + threadIdx.x;
    if (i < n) dinv[i] = rsqrtf((float)(deg[i] + 1));   // +1 = self-loop
}

// ---- exclusive scan of deg -> offs (3-phase) -------------------------------
__global__ void scan1(const int* __restrict__ deg, int* __restrict__ offs,
                      int* __restrict__ bsums, int n) {
    __shared__ int s[SCAN_B];
    int i = blockIdx.x * SCAN_B + threadIdx.x;
    int v = (i < n) ? deg[i] : 0;
    s[threadIdx.x] = v;
    __syncthreads();
    for (int ofs = 1; ofs < SCAN_B; ofs <<= 1) {
        int t = (threadIdx.x >= ofs) ? s[threadIdx.x - ofs] : 0;
        __syncthreads();
        s[threadIdx.x] += t;
        __syncthreads();
    }
    if (i < n) offs[i] = s[threadIdx.x] - v;
    if (threadIdx.x == SCAN_B - 1) bsums[blockIdx.x] = s[SCAN_B - 1];
}

__global__ void scan2(int* __restrict__ bsums, int nb) {
    __shared__ int s[512];
    int v = (threadIdx.x < nb) ? bsums[threadIdx.x] : 0;
    s[threadIdx.x] = v;
    __syncthreads();
    for (int ofs = 1; ofs < 512; ofs <<= 1) {
        int t = (threadIdx.x >= ofs) ? s[threadIdx.x - ofs] : 0;
        __syncthreads();
        s[threadIdx.x] += t;
        __syncthreads();
    }
    if (threadIdx.x < nb) bsums[threadIdx.x] = s[threadIdx.x] - v;
}

__global__ void scan3(int* __restrict__ offs, const int* __restrict__ bsums,
                      int* __restrict__ cursor, int n) {
    int i = blockIdx.x * SCAN_B + threadIdx.x;
    if (i < n) {
        int o = offs[i] + bsums[blockIdx.x];
        offs[i] = o;
        cursor[i] = o;
    }
}

// ---- counting-sort placement: srcs sorted by dst ---------------------------
__global__ void place_kernel(const int* __restrict__ src, const int* __restrict__ dst,
                             int* __restrict__ cursor, int* __restrict__ srcs, int E) {
    int i = blockIdx.x * blockDim.x + threadIdx.x;
    if (i < E) {
        int d = dst[i];
        int pos = atomicAdd(&cursor[d], 1);
        srcs[pos] = src[i];
    }
}

// ---- W pre-swizzle into MFMA B-fragment order, fp32 -> bf16 ----------------
__global__ void prep_W(const float* __restrict__ W1, const float* __restrict__ W2,
                       unsigned short* __restrict__ Wb1, unsigned short* __restrict__ Wb2) {
    int i = blockIdx.x * 256 + threadIdx.x;
    if (i < 4096) {                       // W1: kk(4) x t(8) x lane(64)
        int L = i & 63, t = (i >> 6) & 7, kk = i >> 9;
        int kbase = kk * 32 + (L >> 4) * 8;
        int col = t * 16 + (L & 15);
        unsigned short* o = Wb1 + (size_t)i * 8;
#pragma unroll
        for (int j = 0; j < 8; ++j) o[j] = f2bf(W1[(size_t)(kbase + j) * HID_D + col]);
    } else if (i < 6144) {                // W2: kk(4) x t(4) x lane(64)
        int r = i - 4096;
        int L = r & 63, t = (r >> 6) & 3, kk = r >> 8;
        int kbase = kk * 32 + (L >> 4) * 8;
        int col = t * 16 + (L & 15);
        unsigned short* o = Wb2 + (size_t)r * 8;
#pragma unroll
        for (int j = 0; j < 8; ++j) o[j] = f2bf(W2[(size_t)(kbase + j) * OUT_D + col]);
    }
}

// ---- GEMM1 (MFMA): h[n,128]bf16 = dinv[row] * (x[n,128]f32 @ W1) -----------
__global__ __launch_bounds__(256) void gemm1(const float* __restrict__ x,
                                             const unsigned short* __restrict__ Wb,
                                             const float* __restrict__ dinv,
                                             unsigned short* __restrict__ h, int n) {
    __shared__ __align__(16) unsigned short Ws[4 * 8 * 64 * 8];   // 32 KB
    {
        const uint4* g = (const uint4*)Wb;
        uint4* l = (uint4*)Ws;
        for (int i = threadIdx.x; i < 2048; i += 256) l[i] = g[i];
    }
    const int wave = threadIdx.x >> 6, lane = threadIdx.x & 63;
    const int wrow0 = blockIdx.x * 64 + wave * 16;
    const int mrow = min(wrow0 + (lane & 15), n - 1);
    const float* xr = x + (size_t)mrow * IN_D + ((lane >> 4) * 8);

    float4 a0[4], a1[4];
#pragma unroll
    for (int kk = 0; kk < 4; ++kk) {
        a0[kk] = *(const float4*)(xr + kk * 32);
        a1[kk] = *(const float4*)(xr + kk * 32 + 4);
    }
    BF8 af[4];
#pragma unroll
    for (int kk = 0; kk < 4; ++kk) {
        af[kk].u[0] = f2bf(a0[kk].x); af[kk].u[1] = f2bf(a0[kk].y);
        af[kk].u[2] = f2bf(a0[kk].z); af[kk].u[3] = f2bf(a0[kk].w);
        af[kk].u[4] = f2bf(a1[kk].x); af[kk].u[5] = f2bf(a1[kk].y);
        af[kk].u[6] = f2bf(a1[kk].z); af[kk].u[7] = f2bf(a1[kk].w);
    }
    __syncthreads();

    f32x4 acc[8];
#pragma unroll
    for (int t = 0; t < 8; ++t) acc[t] = (f32x4){0.f, 0.f, 0.f, 0.f};
    const bf8_t* B = (const bf8_t*)Ws;
#pragma unroll
    for (int kk = 0; kk < 4; ++kk) {
#pragma unroll
        for (int t = 0; t < 8; ++t) {
            bf8_t b = B[(kk * 8 + t) * 64 + lane];
            acc[t] = __builtin_amdgcn_mfma_f32_16x16x32_bf16(af[kk].v, b, acc[t], 0, 0, 0);
        }
    }
    const int q = lane >> 4, cbase = lane & 15;
    int rr[4]; float di[4];
#pragma unroll
    for (int r = 0; r < 4; ++r) {
        rr[r] = wrow0 + q * 4 + r;
        di[r] = dinv[min(rr[r], n - 1)];
    }
#pragma unroll
    for (int t = 0; t < 8; ++t) {
        int col = t * 16 + cbase;
#pragma unroll
        for (int r = 0; r < 4; ++r)
            if (rr[r] < n) h[(size_t)rr[r] * HID_D + col] = f2bf(acc[t][r] * di[r]);
    }
}

// ---- GEMM2 (MFMA): g[n,64]bf16 = dinv[row] * (agg[n,128]bf16 @ W2) ---------
__global__ __launch_bounds__(256) void gemm2(const unsigned short* __restrict__ a,
                                             const unsigned short* __restrict__ Wb,
                                             const float* __restrict__ dinv,
                                             unsigned short* __restrict__ g2, int n) {
    __shared__ __align__(16) unsigned short Ws[4 * 4 * 64 * 8];   // 16 KB
    {
        const uint4* g = (const uint4*)Wb;
        uint4* l = (uint4*)Ws;
        for (int i = threadIdx.x; i < 1024; i += 256) l[i] = g[i];
    }
    const int wave = threadIdx.x >> 6, lane = threadIdx.x & 63;
    const int wrow0 = blockIdx.x * 64 + wave * 16;
    const int mrow = min(wrow0 + (lane & 15), n - 1);
    const uint4* ar = (const uint4*)(a + (size_t)mrow * HID_D + ((lane >> 4) * 8));

    BF8 af[4];
#pragma unroll
    for (int kk = 0; kk < 4; ++kk) af[kk].q = ar[kk * 4];
    __syncthreads();

    f32x4 acc[4];
#pragma unroll
    for (int t = 0; t < 4; ++t) acc[t] = (f32x4){0.f, 0.f, 0.f, 0.f};
    const bf8_t* B = (const bf8_t*)Ws;
#pragma unroll
    for (int kk = 0; kk < 4; ++kk) {
#pragma unroll
        for (int t = 0; t < 4; ++t) {
            bf8_t b = B[(kk * 4 + t) * 64 + lane];
            acc[t] = __builtin_amdgcn_mfma_f32_16x16x32_bf16(af[kk].v, b, acc[t], 0, 0, 0);
        }
    }
    const int q = lane >> 4, cbase = lane & 15;
    int rr[4]; float di[4];
#pragma unroll
    for (int r = 0; r < 4; ++r) {
        rr[r] = wrow0 + q * 4 + r;
        di[r] = dinv[min(rr[r], n - 1)];
    }
#pragma unroll
    for (int t = 0; t < 4; ++t) {
        int col = t * 16 + cbase;
#pragma unroll
        for (int r = 0; r < 4; ++r)
            if (rr[r] < n) g2[(size_t)rr[r] * OUT_D + col] = f2bf(acc[t][r] * di[r]);
    }
}

// ---- gather layer 1: 4 nodes/wave (16 lanes each), dwordx4 row chunks ------
// agg[d] = bf16(relu(dinv[d] * (sum_{s in N(d)} h[s] + h[d]) + b))
__global__ __launch_bounds__(256) void gather128(const unsigned short* __restrict__ hp,
                                                 const int* __restrict__ srcs,
                                                 const int* __restrict__ offs,
                                                 const int* __restrict__ deg,
                                                 const float* __restrict__ dinv,
                                                 const float* __restrict__ b,
                                                 uint4* __restrict__ out, int n) {
    int idx  = blockIdx.x * 256 + threadIdx.x;
    int node = idx >> 4;            // one node per 16-lane quad
    int m    = idx & 15;            // 16B chunk index within 256B row
    if (node >= n) return;
    int start = offs[node];
    int k     = deg[node];
    const uint4* tab = (const uint4*)hp + m;    // row stride = 16 uint4

    uint4 u = tab[(size_t)node * 16];           // self-loop term
    float a0[8] = {0, 0, 0, 0, 0, 0, 0, 0};
    float a1[8] = {0, 0, 0, 0, 0, 0, 0, 0};
    acc8(a0, u);
    int j = 0;
    for (; j + 2 <= k; j += 2) {                // 2 independent streams
        int s0 = srcs[start + j];
        int s1 = srcs[start + j + 1];
        uint4 v0 = tab[(size_t)s0 * 16];
        uint4 v1 = tab[(size_t)s1 * 16];
        acc8(a0, v0);
        acc8(a1, v1);
    }
    if (j < k) {
        uint4 v = tab[(size_t)srcs[start + j] * 16];
        acc8(a0, v);
    }
    float di = dinv[node];
    const float* bb = b + m * 8;
    uint4 w;
    float o0, o1;
    o0 = fmaxf((a0[0] + a1[0]) * di + bb[0], 0.f);
    o1 = fmaxf((a0[1] + a1[1]) * di + bb[1], 0.f);
    w.x = (unsigned int)f2bf(o0) | ((unsigned int)f2bf(o1) << 16);
    o0 = fmaxf((a0[2] + a1[2]) * di + bb[2], 0.f);
    o1 = fmaxf((a0[3] + a1[3]) * di + bb[3], 0.f);
    w.y = (unsigned int)f2bf(o0) | ((unsigned int)f2bf(o1) << 16);
    o0 = fmaxf((a0[4] + a1[4]) * di + bb[4], 0.f);
    o1 = fmaxf((a0[5] + a1[5]) * di + bb[5], 0.f);
    w.z = (unsigned int)f2bf(o0) | ((unsigned int)f2bf(o1) << 16);
    o0 = fmaxf((a0[6] + a1[6]) * di + bb[6], 0.f);
    o1 = fmaxf((a0[7] + a1[7]) * di + bb[7], 0.f);
    w.w = (unsigned int)f2bf(o0) | ((unsigned int)f2bf(o1) << 16);
    out[(size_t)node * 16 + m] = w;
}

// ---- gather layer 2: 8 nodes/wave (8 lanes each), dwordx4 row chunks -------
// out[d] = fp32(dinv[d] * (sum g[s] + g[d]) + b)
__global__ __launch_bounds__(256) void gather64(const unsigned short* __restrict__ gp,
                                                const int* __restrict__ srcs,
                                                const int* __restrict__ offs,
                                                const int* __restrict__ deg,
                                                const float* __restrict__ dinv,
                                                const float* __restrict__ b,
                                                float* __restrict__ out, int n) {
    int idx  = blockIdx.x * 256 + threadIdx.x;
    int node = idx >> 3;            // one node per 8-lane group
    int m    = idx & 7;             // 16B chunk index within 128B row
    if (node >= n) return;
    int start = offs[node];
    int k     = deg[node];
    const uint4* tab = (const uint4*)gp + m;    // row stride = 8 uint4

    uint4 u = tab[(size_t)node * 8];            // self-loop term
    float a0[8] = {0, 0, 0, 0, 0, 0, 0, 0};
    float a1[8] = {0, 0, 0, 0, 0, 0, 0, 0};
    acc8(a0, u);
    int j = 0;
    for (; j + 2 <= k; j += 2) {
        int s0 = srcs[start + j];
        int s1 = srcs[start + j + 1];
        uint4 v0 = tab[(size_t)s0 * 8];
        uint4 v1 = tab[(size_t)s1 * 8];
        acc8(a0, v0);
        acc8(a1, v1);
    }
    if (j < k) {
        uint4 v = tab[(size_t)srcs[start + j] * 8];
        acc8(a0, v);
    }
    float di = dinv[node];
    const float* bb = b + m * 8;
    float4 w0, w1;
    w0.x = (a0[0] + a1[0]) * di + bb[0];
    w0.y = (a0[1] + a1[1]) * di + bb[1];
    w0.z = (a0[2] + a1[2]) * di + bb[2];
    w0.w = (a0[3] + a1[3]) * di + bb[3];
    w1.x = (a0[4] + a1[4]) * di + bb[4];
    w1.y = (a0[5] + a1[5]) * di + bb[5];
    w1.z = (a0[6] + a1[6]) * di + bb[6];
    w1.w = (a0[7] + a1[7]) * di + bb[7];
    float* o = out + (size_t)node * OUT_D + m * 8;
    *(float4*)o = w0;
    *(float4*)(o + 4) = w1;
}

extern "C" void kernel_launch(void* const* d_in, const int* in_sizes, int n_in,
                              void* d_out, int out_size, void* d_ws, size_t ws_size,
                              hipStream_t stream) {
    const float* x  = (const float*)d_in[0];
    const int*   ei = (const int*)d_in[1];
    const float* W1 = (const float*)d_in[2];
    const float* b1 = (const float*)d_in[3];
    const float* W2 = (const float*)d_in[4];
    const float* b2 = (const float*)d_in[5];
    float* out = (float*)d_out;

    const int n = in_sizes[0] / IN_D;   // 100000
    const int E = in_sizes[1] / 2;      // 600000
    const int* src = ei;
    const int* dst = ei + E;
    const int nblk = (n + SCAN_B - 1) / SCAN_B;

    // workspace layout (~60 MB)
    char* ws = (char*)d_ws;
    size_t off = 0;
    int*   deg    = (int*)(ws + off);   off += align256((size_t)n * sizeof(int));
    float* dinv   = (float*)(ws + off); off += align256((size_t)n * sizeof(float));
    int*   offs   = (int*)(ws + off);   off += align256((size_t)n * sizeof(int));
    int*   cursor = (int*)(ws + off);   off += align256((size_t)n * sizeof(int));
    int*   bsums  = (int*)(ws + off);   off += align256((size_t)nblk * sizeof(int));
    int*   srcs   = (int*)(ws + off);   off += align256((size_t)E * sizeof(int));
    unsigned short* Wb1 = (unsigned short*)(ws + off); off += align256(4096 * 8 * sizeof(unsigned short));
    unsigned short* Wb2 = (unsigned short*)(ws + off); off += align256(2048 * 8 * sizeof(unsigned short));
    unsigned short* h1  = (unsigned short*)(ws + off); off += align256((size_t)n * HID_D * sizeof(unsigned short));
    unsigned short* agg1= (unsigned short*)(ws + off); off += align256((size_t)n * HID_D * sizeof(unsigned short));
    unsigned short* g2  = h1;   // h1 dead after gather128; reuse

    // --- CSR build + weight prep ---
    hipMemsetAsync(deg, 0, (size_t)n * sizeof(int), stream);
    deg_kernel<<<(E + 255) / 256, 256, 0, stream>>>(dst, E, deg);
    dinv_kernel<<<nblk, SCAN_B, 0, stream>>>(deg, dinv, n);
    scan1<<<nblk, SCAN_B, 0, stream>>>(deg, offs, bsums, n);
    scan2<<<1, 512, 0, stream>>>(bsums, nblk);
    scan3<<<nblk, SCAN_B, 0, stream>>>(offs, bsums, cursor, n);
    place_kernel<<<(E + 255) / 256, 256, 0, stream>>>(src, dst, cursor, srcs, E);
    prep_W<<<24, 256, 0, stream>>>(W1, W2, Wb1, Wb2);

    // --- layer 1 ---
    gemm1<<<(n + 63) / 64, 256, 0, stream>>>(x, Wb1, dinv, h1, n);
    gather128<<<(n + 15) / 16, 256, 0, stream>>>(h1, srcs, offs, deg, dinv, b1,
                                                 (uint4*)agg1, n);

    // --- layer 2 ---
    gemm2<<<(n + 63) / 64, 256, 0, stream>>>(agg1, Wb2, dinv, g2, n);
    gather64<<<(n + 31) / 32, 256, 0, stream>>>(g2, srcs, offs, deg, dinv, b2, out, n);
}

// Round 6
// 233.686 us; speedup vs baseline: 7.6982x; 1.0310x over previous
//
#include <hip/hip_runtime.h>

#define IN_D  128
#define HID_D 128
#define OUT_D 64
#define SCAN_B 256

static inline size_t align256(size_t x) { return (x + 255) & ~(size_t)255; }

typedef short bf8_t  __attribute__((ext_vector_type(8)));   // 8 bf16 (4 VGPRs)
typedef float f32x4  __attribute__((ext_vector_type(4)));   // 4 fp32 acc

union BF8 { bf8_t v; unsigned short u[8]; uint4 q; };

__device__ __forceinline__ unsigned short f2bf(float f) {   // RNE fp32->bf16
    unsigned int u = __float_as_uint(f);
    u += 0x7FFF + ((u >> 16) & 1);
    return (unsigned short)(u >> 16);
}
__device__ __forceinline__ float bflo(unsigned int u) { return __uint_as_float(u << 16); }
__device__ __forceinline__ float bfhi(unsigned int u) { return __uint_as_float(u & 0xFFFF0000u); }

__device__ __forceinline__ void acc8(float* a, uint4 v) {
    a[0] += bflo(v.x); a[1] += bfhi(v.x);
    a[2] += bflo(v.y); a[3] += bfhi(v.y);
    a[4] += bflo(v.z); a[5] += bfhi(v.z);
    a[6] += bflo(v.w); a[7] += bfhi(v.w);
}
__device__ __forceinline__ void accm8(float* a, uint4 v, float msk) {  // masked
    a[0] = fmaf(msk, bflo(v.x), a[0]); a[1] = fmaf(msk, bfhi(v.x), a[1]);
    a[2] = fmaf(msk, bflo(v.y), a[2]); a[3] = fmaf(msk, bfhi(v.y), a[3]);
    a[4] = fmaf(msk, bflo(v.z), a[4]); a[5] = fmaf(msk, bfhi(v.z), a[5]);
    a[6] = fmaf(msk, bflo(v.w), a[6]); a[7] = fmaf(msk, bfhi(v.w), a[7]);
}

// ---- degree histogram ------------------------------------------------------
__global__ void deg_kernel(const int* __restrict__ dst, int E, int* __restrict__ deg) {
    int i = blockIdx.x * blockDim.x + threadIdx.x;
    if (i < E) atomicAdd(&deg[dst[i]], 1);
}

// ---- exclusive scan of deg -> offs (3-phase); scan1 also emits dinv --------
__global__ void scan1(const int* __restrict__ deg, int* __restrict__ offs,
                      int* __restrict__ bsums, float* __restrict__ dinv, int n) {
    __shared__ int s[SCAN_B];
    int i = blockIdx.x * SCAN_B + threadIdx.x;
    int v = (i < n) ? deg[i] : 0;
    if (i < n) dinv[i] = rsqrtf((float)(v + 1));        // +1 = self-loop
    s[threadIdx.x] = v;
    __syncthreads();
    for (int ofs = 1; ofs < SCAN_B; ofs <<= 1) {
        int t = (threadIdx.x >= ofs) ? s[threadIdx.x - ofs] : 0;
        __syncthreads();
        s[threadIdx.x] += t;
        __syncthreads();
    }
    if (i < n) offs[i] = s[threadIdx.x] - v;
    if (threadIdx.x == SCAN_B - 1) bsums[blockIdx.x] = s[SCAN_B - 1];
}

__global__ void scan2(int* __restrict__ bsums, int nb) {
    __shared__ int s[512];
    int v = (threadIdx.x < nb) ? bsums[threadIdx.x] : 0;
    s[threadIdx.x] = v;
    __syncthreads();
    for (int ofs = 1; ofs < 512; ofs <<= 1) {
        int t = (threadIdx.x >= ofs) ? s[threadIdx.x - ofs] : 0;
        __syncthreads();
        s[threadIdx.x] += t;
        __syncthreads();
    }
    if (threadIdx.x < nb) bsums[threadIdx.x] = s[threadIdx.x] - v;
}

__global__ void scan3(int* __restrict__ offs, const int* __restrict__ bsums,
                      int* __restrict__ cursor, int n) {
    int i = blockIdx.x * SCAN_B + threadIdx.x;
    if (i < n) {
        int o = offs[i] + bsums[blockIdx.x];
        offs[i] = o;
        cursor[i] = o;
    }
}

// ---- counting-sort placement: srcs sorted by dst ---------------------------
__global__ void place_kernel(const int* __restrict__ src, const int* __restrict__ dst,
                             int* __restrict__ cursor, int* __restrict__ srcs, int E) {
    int i = blockIdx.x * blockDim.x + threadIdx.x;
    if (i < E) {
        int d = dst[i];
        int pos = atomicAdd(&cursor[d], 1);
        srcs[pos] = src[i];
    }
}

// ---- W pre-swizzle into MFMA B-fragment order, fp32 -> bf16 ----------------
__global__ void prep_W(const float* __restrict__ W1, const float* __restrict__ W2,
                       unsigned short* __restrict__ Wb1, unsigned short* __restrict__ Wb2) {
    int i = blockIdx.x * 256 + threadIdx.x;
    if (i < 4096) {                       // W1: kk(4) x t(8) x lane(64)
        int L = i & 63, t = (i >> 6) & 7, kk = i >> 9;
        int kbase = kk * 32 + (L >> 4) * 8;
        int col = t * 16 + (L & 15);
        unsigned short* o = Wb1 + (size_t)i * 8;
#pragma unroll
        for (int j = 0; j < 8; ++j) o[j] = f2bf(W1[(size_t)(kbase + j) * HID_D + col]);
    } else if (i < 6144) {                // W2: kk(4) x t(4) x lane(64)
        int r = i - 4096;
        int L = r & 63, t = (r >> 6) & 3, kk = r >> 8;
        int kbase = kk * 32 + (L >> 4) * 8;
        int col = t * 16 + (L & 15);
        unsigned short* o = Wb2 + (size_t)r * 8;
#pragma unroll
        for (int j = 0; j < 8; ++j) o[j] = f2bf(W2[(size_t)(kbase + j) * OUT_D + col]);
    }
}

// ---- GEMM1 (MFMA): h[n,128]bf16 = dinv[row] * (x[n,128]f32 @ W1) -----------
__global__ __launch_bounds__(256) void gemm1(const float* __restrict__ x,
                                             const unsigned short* __restrict__ Wb,
                                             const float* __restrict__ dinv,
                                             unsigned short* __restrict__ h, int n) {
    __shared__ __align__(16) unsigned short Ws[4 * 8 * 64 * 8];   // 32 KB
    {
        const uint4* g = (const uint4*)Wb;
        uint4* l = (uint4*)Ws;
        for (int i = threadIdx.x; i < 2048; i += 256) l[i] = g[i];
    }
    const int wave = threadIdx.x >> 6, lane = threadIdx.x & 63;
    const int wrow0 = blockIdx.x * 64 + wave * 16;
    const int mrow = min(wrow0 + (lane & 15), n - 1);
    const float* xr = x + (size_t)mrow * IN_D + ((lane >> 4) * 8);

    float4 a0[4], a1[4];
#pragma unroll
    for (int kk = 0; kk < 4; ++kk) {
        a0[kk] = *(const float4*)(xr + kk * 32);
        a1[kk] = *(const float4*)(xr + kk * 32 + 4);
    }
    BF8 af[4];
#pragma unroll
    for (int kk = 0; kk < 4; ++kk) {
        af[kk].u[0] = f2bf(a0[kk].x); af[kk].u[1] = f2bf(a0[kk].y);
        af[kk].u[2] = f2bf(a0[kk].z); af[kk].u[3] = f2bf(a0[kk].w);
        af[kk].u[4] = f2bf(a1[kk].x); af[kk].u[5] = f2bf(a1[kk].y);
        af[kk].u[6] = f2bf(a1[kk].z); af[kk].u[7] = f2bf(a1[kk].w);
    }
    __syncthreads();

    f32x4 acc[8];
#pragma unroll
    for (int t = 0; t < 8; ++t) acc[t] = (f32x4){0.f, 0.f, 0.f, 0.f};
    const bf8_t* B = (const bf8_t*)Ws;
#pragma unroll
    for (int kk = 0; kk < 4; ++kk) {
#pragma unroll
        for (int t = 0; t < 8; ++t) {
            bf8_t b = B[(kk * 8 + t) * 64 + lane];
            acc[t] = __builtin_amdgcn_mfma_f32_16x16x32_bf16(af[kk].v, b, acc[t], 0, 0, 0);
        }
    }
    const int q = lane >> 4, cbase = lane & 15;
    int rr[4]; float di[4];
#pragma unroll
    for (int r = 0; r < 4; ++r) {
        rr[r] = wrow0 + q * 4 + r;
        di[r] = dinv[min(rr[r], n - 1)];
    }
#pragma unroll
    for (int t = 0; t < 8; ++t) {
        int col = t * 16 + cbase;
#pragma unroll
        for (int r = 0; r < 4; ++r)
            if (rr[r] < n) h[(size_t)rr[r] * HID_D + col] = f2bf(acc[t][r] * di[r]);
    }
}

// ---- GEMM2 (MFMA): g[n,64]bf16 = dinv[row] * (agg[n,128]bf16 @ W2) ---------
__global__ __launch_bounds__(256) void gemm2(const unsigned short* __restrict__ a,
                                             const unsigned short* __restrict__ Wb,
                                             const float* __restrict__ dinv,
                                             unsigned short* __restrict__ g2, int n) {
    __shared__ __align__(16) unsigned short Ws[4 * 4 * 64 * 8];   // 16 KB
    {
        const uint4* g = (const uint4*)Wb;
        uint4* l = (uint4*)Ws;
        for (int i = threadIdx.x; i < 1024; i += 256) l[i] = g[i];
    }
    const int wave = threadIdx.x >> 6, lane = threadIdx.x & 63;
    const int wrow0 = blockIdx.x * 64 + wave * 16;
    const int mrow = min(wrow0 + (lane & 15), n - 1);
    const uint4* ar = (const uint4*)(a + (size_t)mrow * HID_D + ((lane >> 4) * 8));

    BF8 af[4];
#pragma unroll
    for (int kk = 0; kk < 4; ++kk) af[kk].q = ar[kk * 4];
    __syncthreads();

    f32x4 acc[4];
#pragma unroll
    for (int t = 0; t < 4; ++t) acc[t] = (f32x4){0.f, 0.f, 0.f, 0.f};
    const bf8_t* B = (const bf8_t*)Ws;
#pragma unroll
    for (int kk = 0; kk < 4; ++kk) {
#pragma unroll
        for (int t = 0; t < 4; ++t) {
            bf8_t b = B[(kk * 4 + t) * 64 + lane];
            acc[t] = __builtin_amdgcn_mfma_f32_16x16x32_bf16(af[kk].v, b, acc[t], 0, 0, 0);
        }
    }
    const int q = lane >> 4, cbase = lane & 15;
    int rr[4]; float di[4];
#pragma unroll
    for (int r = 0; r < 4; ++r) {
        rr[r] = wrow0 + q * 4 + r;
        di[r] = dinv[min(rr[r], n - 1)];
    }
#pragma unroll
    for (int t = 0; t < 4; ++t) {
        int col = t * 16 + cbase;
#pragma unroll
        for (int r = 0; r < 4; ++r)
            if (rr[r] < n) g2[(size_t)rr[r] * OUT_D + col] = f2bf(acc[t][r] * di[r]);
    }
}

// ---- gather layer 1: 4 nodes/wave (16 lanes each), 8-deep load batches -----
// agg[d] = bf16(relu(dinv[d] * (sum_{s in N(d)} h[s] + h[d]) + b))
__global__ __launch_bounds__(256) void gather128(const unsigned short* __restrict__ hp,
                                                 const int* __restrict__ srcs,
                                                 const int* __restrict__ offs,
                                                 const int* __restrict__ deg,
                                                 const float* __restrict__ dinv,
                                                 const float* __restrict__ b,
                                                 uint4* __restrict__ out, int n) {
    int idx  = blockIdx.x * 256 + threadIdx.x;
    int node = idx >> 4;            // one node per 16-lane quad
    int m    = idx & 15;            // 16B chunk index within 256B row
    if (node >= n) return;
    int start = offs[node];
    int k     = deg[node];
    const uint4* tab = (const uint4*)hp + m;    // row stride = 16 uint4

    uint4 u = tab[(size_t)node * 16];           // self-loop term
    float a[8] = {0, 0, 0, 0, 0, 0, 0, 0};
    acc8(a, u);
    for (int j0 = 0; j0 < k; j0 += 8) {         // 8 independent loads per batch
        int is[8];
#pragma unroll
        for (int t = 0; t < 8; ++t) is[t] = srcs[start + min(j0 + t, k - 1)];
        uint4 v[8];
#pragma unroll
        for (int t = 0; t < 8; ++t) v[t] = tab[(size_t)is[t] * 16];
#pragma unroll
        for (int t = 0; t < 8; ++t) {
            float msk = (j0 + t < k) ? 1.0f : 0.0f;
            accm8(a, v[t], msk);
        }
    }
    float di = dinv[node];
    const float* bb = b + m * 8;
    uint4 w;
    float o0, o1;
    o0 = fmaxf(a[0] * di + bb[0], 0.f);
    o1 = fmaxf(a[1] * di + bb[1], 0.f);
    w.x = (unsigned int)f2bf(o0) | ((unsigned int)f2bf(o1) << 16);
    o0 = fmaxf(a[2] * di + bb[2], 0.f);
    o1 = fmaxf(a[3] * di + bb[3], 0.f);
    w.y = (unsigned int)f2bf(o0) | ((unsigned int)f2bf(o1) << 16);
    o0 = fmaxf(a[4] * di + bb[4], 0.f);
    o1 = fmaxf(a[5] * di + bb[5], 0.f);
    w.z = (unsigned int)f2bf(o0) | ((unsigned int)f2bf(o1) << 16);
    o0 = fmaxf(a[6] * di + bb[6], 0.f);
    o1 = fmaxf(a[7] * di + bb[7], 0.f);
    w.w = (unsigned int)f2bf(o0) | ((unsigned int)f2bf(o1) << 16);
    out[(size_t)node * 16 + m] = w;
}

// ---- gather layer 2: 8 nodes/wave (8 lanes each), 8-deep load batches ------
// out[d] = fp32(dinv[d] * (sum g[s] + g[d]) + b)
__global__ __launch_bounds__(256) void gather64(const unsigned short* __restrict__ gp,
                                                const int* __restrict__ srcs,
                                                const int* __restrict__ offs,
                                                const int* __restrict__ deg,
                                                const float* __restrict__ dinv,
                                                const float* __restrict__ b,
                                                float* __restrict__ out, int n) {
    int idx  = blockIdx.x * 256 + threadIdx.x;
    int node = idx >> 3;            // one node per 8-lane group
    int m    = idx & 7;             // 16B chunk index within 128B row
    if (node >= n) return;
    int start = offs[node];
    int k     = deg[node];
    const uint4* tab = (const uint4*)gp + m;    // row stride = 8 uint4

    uint4 u = tab[(size_t)node * 8];            // self-loop term
    float a[8] = {0, 0, 0, 0, 0, 0, 0, 0};
    acc8(a, u);
    for (int j0 = 0; j0 < k; j0 += 8) {
        int is[8];
#pragma unroll
        for (int t = 0; t < 8; ++t) is[t] = srcs[start + min(j0 + t, k - 1)];
        uint4 v[8];
#pragma unroll
        for (int t = 0; t < 8; ++t) v[t] = tab[(size_t)is[t] * 8];
#pragma unroll
        for (int t = 0; t < 8; ++t) {
            float msk = (j0 + t < k) ? 1.0f : 0.0f;
            accm8(a, v[t], msk);
        }
    }
    float di = dinv[node];
    const float* bb = b + m * 8;
    float4 w0, w1;
    w0.x = a[0] * di + bb[0];
    w0.y = a[1] * di + bb[1];
    w0.z = a[2] * di + bb[2];
    w0.w = a[3] * di + bb[3];
    w1.x = a[4] * di + bb[4];
    w1.y = a[5] * di + bb[5];
    w1.z = a[6] * di + bb[6];
    w1.w = a[7] * di + bb[7];
    float* o = out + (size_t)node * OUT_D + m * 8;
    *(float4*)o = w0;
    *(float4*)(o + 4) = w1;
}

extern "C" void kernel_launch(void* const* d_in, const int* in_sizes, int n_in,
                              void* d_out, int out_size, void* d_ws, size_t ws_size,
                              hipStream_t stream) {
    const float* x  = (const float*)d_in[0];
    const int*   ei = (const int*)d_in[1];
    const float* W1 = (const float*)d_in[2];
    const float* b1 = (const float*)d_in[3];
    const float* W2 = (const float*)d_in[4];
    const float* b2 = (const float*)d_in[5];
    float* out = (float*)d_out;

    const int n = in_sizes[0] / IN_D;   // 100000
    const int E = in_sizes[1] / 2;      // 600000
    const int* src = ei;
    const int* dst = ei + E;
    const int nblk = (n + SCAN_B - 1) / SCAN_B;

    // workspace layout (~60 MB)
    char* ws = (char*)d_ws;
    size_t off = 0;
    int*   deg    = (int*)(ws + off);   off += align256((size_t)n * sizeof(int));
    float* dinv   = (float*)(ws + off); off += align256((size_t)n * sizeof(float));
    int*   offs   = (int*)(ws + off);   off += align256((size_t)n * sizeof(int));
    int*   cursor = (int*)(ws + off);   off += align256((size_t)n * sizeof(int));
    int*   bsums  = (int*)(ws + off);   off += align256((size_t)nblk * sizeof(int));
    int*   srcs   = (int*)(ws + off);   off += align256((size_t)E * sizeof(int));
    unsigned short* Wb1 = (unsigned short*)(ws + off); off += align256(4096 * 8 * sizeof(unsigned short));
    unsigned short* Wb2 = (unsigned short*)(ws + off); off += align256(2048 * 8 * sizeof(unsigned short));
    unsigned short* h1  = (unsigned short*)(ws + off); off += align256((size_t)n * HID_D * sizeof(unsigned short));
    unsigned short* agg1= (unsigned short*)(ws + off); off += align256((size_t)n * HID_D * sizeof(unsigned short));
    unsigned short* g2  = h1;   // h1 dead after gather128; reuse

    // --- CSR build + weight prep ---
    hipMemsetAsync(deg, 0, (size_t)n * sizeof(int), stream);
    deg_kernel<<<(E + 255) / 256, 256, 0, stream>>>(dst, E, deg);
    scan1<<<nblk, SCAN_B, 0, stream>>>(deg, offs, bsums, dinv, n);
    scan2<<<1, 512, 0, stream>>>(bsums, nblk);
    scan3<<<nblk, SCAN_B, 0, stream>>>(offs, bsums, cursor, n);
    place_kernel<<<(E + 255) / 256, 256, 0, stream>>>(src, dst, cursor, srcs, E);
    prep_W<<<24, 256, 0, stream>>>(W1, W2, Wb1, Wb2);

    // --- layer 1 ---
    gemm1<<<(n + 63) / 64, 256, 0, stream>>>(x, Wb1, dinv, h1, n);
    gather128<<<(n + 15) / 16, 256, 0, stream>>>(h1, srcs, offs, deg, dinv, b1,
                                                 (uint4*)agg1, n);

    // --- layer 2 ---
    gemm2<<<(n + 63) / 64, 256, 0, stream>>>(agg1, Wb2, dinv, g2, n);
    gather64<<<(n + 31) / 32, 256, 0, stream>>>(g2, srcs, offs, deg, dinv, b2, out, n);
}